// Round 8
// baseline (8841.202 us; speedup 1.0000x reference)
//
#include <hip/hip_runtime.h>
#include <math.h>

// Problem constants
#define B_ROWS 8192
#define S_LEN  512
#define H_DIM  256
#define G3     768          // 3*H
#define P_DIM  96
#define TB     32           // batch rows per block

typedef __attribute__((ext_vector_type(8))) short short8;   // 8 bf16 (4 VGPRs)
typedef __attribute__((ext_vector_type(4))) float floatx4;  // MFMA C/D frag

__device__ __forceinline__ float sigmoid_fast(float v) {
    return 1.0f / (1.0f + __expf(-v));
}
__device__ __forceinline__ float tanh_fast(float v) {
    return 1.0f - 2.0f / (__expf(2.0f * v) + 1.0f);
}
__device__ __forceinline__ unsigned short f32_bf16_rtn(float f) {
    unsigned int u = __float_as_uint(f);
    u += 0x7fffu + ((u >> 16) & 1u);   // round-to-nearest-even
    return (unsigned short)(u >> 16);
}
__device__ __forceinline__ float bf16_f32(unsigned short h) {
    return __uint_as_float(((unsigned int)h) << 16);
}

// -------- One-time weight pack: W_hh -> per-lane MFMA B-fragments (hi/lo bf16).
// B[k][n] = W_hh[n][k].  16x16x32 B-frag: lane holds B[n=lane&15][k=quad*8+j].
// Tile index = (k>>5)*48 + (j>>4); lane = (j&15) | (((k>>3)&3)<<4); short = k&7.
// Also WoT[k][p] = W_out[p][k]; also zeroes the phase-sync counter.
__global__ void pack_weights(const float* __restrict__ W_hh,
                             const float* __restrict__ W_out,
                             unsigned short* __restrict__ Bh,
                             unsigned short* __restrict__ Bl,
                             float* __restrict__ WoT,
                             unsigned int* __restrict__ ctr) {
    const int j = blockIdx.x;    // gate col 0..767
    const int k = threadIdx.x;   // h idx   0..255
    const float wv = W_hh[j * H_DIM + k];
    const unsigned short hi = f32_bf16_rtn(wv);
    const unsigned short lo = f32_bf16_rtn(wv - bf16_f32(hi));
    const int idx = (((k >> 5) * 48 + (j >> 4)) * 64 +
                     ((j & 15) | (((k >> 3) & 3) << 4))) * 8 + (k & 7);
    Bh[idx] = hi;
    Bl[idx] = lo;
    if (j < P_DIM) WoT[k * P_DIM + j] = W_out[j * H_DIM + k];
    if (j == 0 && k == 0) *ctr = 0u;   // d_ws is re-poisoned every launch
}

// LDS layout (~148 KiB):
//   [0,       65536)  A-fragments, double-buffered: buf*32768 + (hi/lo)*16384
//                     + chunk(kc*2+mt)*1024 + slot*16 + short*2, slot = g(row),
//                     g(v) = v ^ ((v>>2)&7)  (reads conflict-free per 8-lane
//                     group, writes hit 8 distinct bank groups)
//   [65536,   69888)  xtile[2][32][17] fp32 (stride 17 kills bcast conflicts)
//   [69888,  151808)  W cache: 80 tiles x 1 KiB
//                     slots 0..47  = kc=6 lo  (index g*16 + w*2 + ht)
//                     slots 48..79 = kc=5 hi, g<2 (index g*16 + w*2 + ht)
#define A_OFF   0
#define X_OFF   65536
#define W_OFF   69888
#define LDS_SZ  151808
#define XSTR    17

union U16 { uint4 u; short8 s; };

__device__ __forceinline__ void mfma3(floatx4& c0, floatx4& c1,
                                      const short8& ah0, const short8& ah1,
                                      const short8& al0, const short8& al1,
                                      const short8& bh, const short8& bl) {
    c0 = __builtin_amdgcn_mfma_f32_16x16x32_bf16(ah0, bh, c0, 0, 0, 0);
    c1 = __builtin_amdgcn_mfma_f32_16x16x32_bf16(ah1, bh, c1, 0, 0, 0);
    c0 = __builtin_amdgcn_mfma_f32_16x16x32_bf16(al0, bh, c0, 0, 0, 0);
    c1 = __builtin_amdgcn_mfma_f32_16x16x32_bf16(al1, bh, c1, 0, 0, 0);
    c0 = __builtin_amdgcn_mfma_f32_16x16x32_bf16(ah0, bl, c0, 0, 0, 0);
    c1 = __builtin_amdgcn_mfma_f32_16x16x32_bf16(ah1, bl, c1, 0, 0, 0);
}

// A-frag reads for chunk kc_ (4 x ds_read_b128, swizzled rows).
#define READ_A(kc_) {                                                \
    const int cb = ((kc_) * 2) << 10;                                \
    ah0 = *(const short8*)(Ah + cb + rl16);                          \
    ah1 = *(const short8*)(Ah + cb + 1024 + rl16);                   \
    al0 = *(const short8*)(Al + cb + rl16);                          \
    al1 = *(const short8*)(Al + cb + 1024 + rl16); }

// Issue the 6 loads (3 gh, hi+lo) of half-group ghb_ of chunk kc_ into G_.
#define LOAD_G(G_, kc_, ghb_) {                                      \
    const size_t kb = (size_t)(kc_) * 49152;                         \
    _Pragma("unroll") for (int i_ = 0; i_ < 3; ++i_) {               \
        G_[2 * i_].u     = *(const uint4*)(BhB + kb + boff[(ghb_) + i_]); \
        G_[2 * i_ + 1].u = *(const uint4*)(BlB + kb + boff[(ghb_) + i_]); \
    } }

// 18 MFMAs consuming half-group G_ (gh = ghb_..ghb_+2) with current A-frags.
#define MFMA_G(G_, ghb_)                                             \
    _Pragma("unroll") for (int i_ = 0; i_ < 3; ++i_) {               \
        mfma3(acc[((ghb_) + i_) >> 1][0][((ghb_) + i_) & 1],         \
              acc[((ghb_) + i_) >> 1][1][((ghb_) + i_) & 1],         \
              ah0, ah1, al0, al1, G_[2 * i_].s, G_[2 * i_ + 1].s);   \
    }

// kc=5 streamed remainders: P gets gh0-3 lo; Q gets gh4,5 hi+lo.
#define LOAD_K5P(P_) { const size_t kb = (size_t)5 * 49152;          \
    _Pragma("unroll") for (int i_ = 0; i_ < 4; ++i_)                 \
        P_[i_].u = *(const uint4*)(BlB + kb + boff[i_]); }
#define LOAD_K5Q(Q_) { const size_t kb = (size_t)5 * 49152;          \
    Q_[0].u = *(const uint4*)(BhB + kb + boff[4]);                   \
    Q_[1].u = *(const uint4*)(BlB + kb + boff[4]);                   \
    Q_[2].u = *(const uint4*)(BhB + kb + boff[5]);                   \
    Q_[3].u = *(const uint4*)(BlB + kb + boff[5]); }

// Main persistent GRU kernel: split-bf16 MFMA + partial weight residency +
// half-kc software pipeline. Transient B regs capped at P+Q = 48 VGPRs (the
// R4-proven no-spill envelope); resident chunks run first to hide the first
// group's L2 latency. grid = 256 (1 block/CU), block = 512 (8 waves, 2/SIMD).
__global__ __launch_bounds__(512, 2)
void gru_mfma(const float* __restrict__ x,
              const float* __restrict__ W_ih,
              const float* __restrict__ b_ih,
              const float* __restrict__ b_hh,
              const unsigned short* __restrict__ Bh,
              const unsigned short* __restrict__ Bl,
              const float* __restrict__ WoT,   // [256][96]
              const float* __restrict__ b_out,
              float* __restrict__ out,
              unsigned int* __restrict__ ctr) {
    __shared__ __align__(16) char smem[LDS_SZ];

    const int tid  = threadIdx.x;
    const int w    = tid >> 6;     // wave 0..7
    const int lane = tid & 63;
    const int q    = lane >> 4;    // quad
    const int c    = lane & 15;
    const int row0 = blockIdx.x * TB;

    const char* BhB = (const char*)Bh;
    const char* BlB = (const char*)Bl;

    // Per-thread gate params; col = 256*g + 32*w + 16*ht + c
    float wih[3][2], bcc[2][2], bihn[2], bhhn[2];
#pragma unroll
    for (int g = 0; g < 3; ++g)
#pragma unroll
        for (int ht = 0; ht < 2; ++ht) {
            const int col = g * H_DIM + w * 32 + ht * 16 + c;
            wih[g][ht] = W_ih[col];
            if (g < 2) {
                bcc[g][ht] = b_ih[col] + b_hh[col];
            } else {
                bihn[ht] = b_ih[col];
                bhhn[ht] = b_hh[col];
            }
        }

    // 32-bit per-lane tile offsets (gh = g*2 + ht); chunk kc adds kc*49152.
    unsigned int boff[6];
#pragma unroll
    for (int gh = 0; gh < 6; ++gh)
        boff[gh] = (unsigned)((((gh >> 1) * 16 + w * 2 + (gh & 1)) << 10) + (lane << 4));

    // Register-resident weight tiles: kc=7 hi+lo, kc=6 hi.  (72 VGPRs)
    short8 r7h[6], r7l[6], r6h[6];
#pragma unroll
    for (int gh = 0; gh < 6; ++gh) {
        U16 a, b, d;
        a.u = *(const uint4*)(BhB + (size_t)7 * 49152 + boff[gh]);
        b.u = *(const uint4*)(BlB + (size_t)7 * 49152 + boff[gh]);
        d.u = *(const uint4*)(BhB + (size_t)6 * 49152 + boff[gh]);
        r7h[gh] = a.s; r7l[gh] = b.s; r6h[gh] = d.s;
    }

    // LDS weight cache staging: 80 tiles (kc=6 lo: Bl tiles 288..335;
    // kc=5 hi g<2: Bh tiles 240..271).
    for (int i = tid; i < 80 * 64; i += 512) {
        const int slot = i >> 6, l16 = i & 63;
        const unsigned short* src = (slot < 48)
            ? (Bl + (size_t)(288 + slot) * 512 + l16 * 8)
            : (Bh + (size_t)(240 + slot - 48) * 512 + l16 * 8);
        *(uint4*)(smem + W_OFF + slot * 1024 + l16 * 16) = *(const uint4*)src;
    }

    // Zero both A-frag buffers (h0 = 0) and stage x for t=0..15.
    for (int i = tid; i < 16384; i += 512) ((int*)(smem + A_OFF))[i] = 0;
    float* xt = (float*)(smem + X_OFF);
    {
        const int r = tid >> 4, t2 = tid & 15;
        xt[r * XSTR + t2] = x[(size_t)(row0 + r) * S_LEN + t2];
    }
    __syncthreads();

    // h_old in C-frag layout: element (mt,ht,reg) = h[4q+reg+16mt][32w+16ht+c]
    float h_own[2][2][4];
#pragma unroll
    for (int mt = 0; mt < 2; ++mt)
#pragma unroll
        for (int ht = 0; ht < 2; ++ht)
#pragma unroll
            for (int r = 0; r < 4; ++r) h_own[mt][ht][r] = 0.0f;

    // Swizzle g(v) = v ^ ((v>>2)&7): reads conflict-free per aligned 8-lane
    // group; writer dest rows hit 8 distinct bank groups per store.
    const int rl16 = (lane ^ ((lane >> 2) & 7)) << 4;
    const int gxor = q + 4 * (c >> 3);       // == (d>>2)&7, thread-constant

    for (int t = 0; t < S_LEN; ++t) {
        const int cur = t & 1, nxt = cur ^ 1;
        const char* Ah = smem + A_OFF + cur * 32768;
        const char* Al = Ah + 16384;

        // x for my 8 rows (LDS broadcast, conflict-free via XSTR=17)
        float xr[2][4];
#pragma unroll
        for (int mt = 0; mt < 2; ++mt)
#pragma unroll
            for (int r = 0; r < 4; ++r)
                xr[mt][r] = xt[(((t >> 4) & 1) * 32 + q * 4 + r + 16 * mt) * XSTR + (t & 15)];

        // C frags [gate][mt][ht]; fold x-side pre-activation + bias into init.
        floatx4 acc[3][2][2];
#pragma unroll
        for (int mt = 0; mt < 2; ++mt)
#pragma unroll
            for (int ht = 0; ht < 2; ++ht)
#pragma unroll
                for (int r = 0; r < 4; ++r) {
                    acc[0][mt][ht][r] = fmaf(xr[mt][r], wih[0][ht], bcc[0][ht]);
                    acc[1][mt][ht][r] = fmaf(xr[mt][r], wih[1][ht], bcc[1][ht]);
                    acc[2][mt][ht][r] = bhhn[ht];
                }

        U16 P[6], Q[6];
        short8 ah0, ah1, al0, al1;

        // ---- Prologue: issue kc0's two half-groups, hide their latency
        // under the register/LDS-resident chunks kc7 and kc6. ----
        LOAD_G(P, 0, 0)
        READ_A(7)
#pragma unroll
        for (int gh = 0; gh < 6; ++gh)
            mfma3(acc[gh >> 1][0][gh & 1], acc[gh >> 1][1][gh & 1],
                  ah0, ah1, al0, al1, r7h[gh], r7l[gh]);
        LOAD_G(Q, 0, 3)
        READ_A(6)
#pragma unroll
        for (int gh = 0; gh < 6; ++gh) {
            const int slot = (gh >> 1) * 16 + w * 2 + (gh & 1);
            short8 bl = *(const short8*)(smem + W_OFF + slot * 1024 + lane * 16);
            mfma3(acc[gh >> 1][0][gh & 1], acc[gh >> 1][1][gh & 1],
                  ah0, ah1, al0, al1, r6h[gh], bl);
        }

        // ---- kc = 0..3: half-kc ping-pong pipeline.  Consume P, refill P
        // for kc+1 (in flight across MFMA_G(Q) + next iteration). Peak
        // transient = P+Q = 48 VGPRs = R4's proven no-spill envelope. ----
#pragma unroll 1
        for (int kc = 0; kc < 4; ++kc) {
            READ_A(kc)
            MFMA_G(P, 0)
            LOAD_G(P, kc + 1, 0)
            MFMA_G(Q, 3)
            LOAD_G(Q, kc + 1, 3)
        }

        // ---- kc = 4: consume, refill with kc5's streamed remainders ----
        READ_A(4)
        MFMA_G(P, 0)
        LOAD_K5P(P)
        MFMA_G(Q, 3)
        LOAD_K5Q(Q)

        // ---- kc = 5: hi g<2 from LDS cache; rest from P/Q ----
        READ_A(5)
#pragma unroll
        for (int gh = 0; gh < 4; ++gh) {
            const int slot = 48 + (gh >> 1) * 16 + w * 2 + (gh & 1);
            short8 bh = *(const short8*)(smem + W_OFF + slot * 1024 + lane * 16);
            mfma3(acc[gh >> 1][0][gh & 1], acc[gh >> 1][1][gh & 1],
                  ah0, ah1, al0, al1, bh, P[gh].s);
        }
        mfma3(acc[2][0][0], acc[2][1][0], ah0, ah1, al0, al1, Q[0].s, Q[1].s);
        mfma3(acc[2][0][1], acc[2][1][1], ah0, ah1, al0, al1, Q[2].s, Q[3].s);

        // Gates + h update (in-register); scatter next A-frags (g-swizzled).
        char* Anx = smem + A_OFF + nxt * 32768;
#pragma unroll
        for (int mt = 0; mt < 2; ++mt) {
            char* chh = Anx + (w * 2 + mt) * 1024;          // hi chunk (kc=w)
            char* cll = chh + 16384;                        // lo chunk
#pragma unroll
            for (int ht = 0; ht < 2; ++ht)
#pragma unroll
                for (int r = 0; r < 4; ++r) {
                    const float rr  = sigmoid_fast(acc[0][mt][ht][r]);
                    const float zz  = sigmoid_fast(acc[1][mt][ht][r]);
                    const float inn = fmaf(xr[mt][r], wih[2][ht], bihn[ht]);
                    const float nn  = tanh_fast(fmaf(rr, acc[2][mt][ht][r], inn));
                    const float hv  = (1.0f - zz) * nn + zz * h_own[mt][ht][r];
                    h_own[mt][ht][r] = hv;
                    const unsigned short hi = f32_bf16_rtn(hv);
                    // lo truncated (error 2^-17-relative, invisible vs 2^-11)
                    const unsigned short lo =
                        (unsigned short)(__float_as_uint(hv - bf16_f32(hi)) >> 16);
                    const int d   = (q * 4 + r) | ((2 * ht + (c >> 3)) << 4);
                    const int off = ((d ^ gxor) << 4) + ((c & 7) << 1);
                    *(unsigned short*)(chh + off) = hi;
                    *(unsigned short*)(cll + off) = lo;
                }
        }

        // Re-stage x for the next 16 steps (into the idle x buffer).
        const bool tick = ((t & 15) == 15) && (t != S_LEN - 1);
        if (tick) {
            const int r = tid >> 4, t2 = tid & 15;
            xt[((((t + 1) >> 4) & 1) * 32 + r) * XSTR + t2] =
                x[(size_t)(row0 + r) * S_LEN + (t + 1) + t2];
        }
        __syncthreads();   // single barrier: next A-frags + x tile visible

        // Phase-alignment heartbeat every 16 steps: keeps all 256 blocks'
        // weight streams in phase so per-XCD L2 stays hot.  Pure timing
        // hint — bounded spin, no data dependency.
        if (tick) {
            if (tid == 0) {
                const unsigned int tgt = 256u * (unsigned)((t >> 4) + 1);
                atomicAdd(ctr, 1u);
                for (int spin = 0; spin < (1 << 17); ++spin) {
                    if (__hip_atomic_load(ctr, __ATOMIC_RELAXED,
                                          __HIP_MEMORY_SCOPE_AGENT) >= tgt) break;
                    __builtin_amdgcn_s_sleep(4);
                }
            }
            __syncthreads();
        }
    }

    // -------- Epilogue: dump final h (fp32, from registers) and project.
    float* hfin = (float*)(smem);   // reuse A region: [32][256]
#pragma unroll
    for (int mt = 0; mt < 2; ++mt)
#pragma unroll
        for (int ht = 0; ht < 2; ++ht)
#pragma unroll
            for (int r = 0; r < 4; ++r) {
                const int m = q * 4 + r + 16 * mt;
                const int k = w * 32 + ht * 16 + c;
                hfin[m * H_DIM + k] = h_own[mt][ht][r];
            }
    __syncthreads();

    if (tid < 256) {
        const int cid   = tid & 63;
        const int rid   = tid >> 6;
        const int myrow = rid * 8;
        const int pA    = cid;
        const int pB    = 64 + cid;
        const bool hasB = (cid < 32);
        float accA[8], accB[8];
#pragma unroll
        for (int rr = 0; rr < 8; ++rr) { accA[rr] = 0.0f; accB[rr] = 0.0f; }

        for (int k = 0; k < H_DIM; k += 4) {
            float4 hv[8];
#pragma unroll
            for (int rr = 0; rr < 8; ++rr)
                hv[rr] = *(const float4*)&hfin[(myrow + rr) * H_DIM + k];
            float wA[4], wB[4];
#pragma unroll
            for (int kk = 0; kk < 4; ++kk) {
                wA[kk] = WoT[(size_t)(k + kk) * P_DIM + pA];
                wB[kk] = hasB ? WoT[(size_t)(k + kk) * P_DIM + pB] : 0.0f;
            }
#pragma unroll
            for (int kk = 0; kk < 4; ++kk)
#pragma unroll
                for (int rr = 0; rr < 8; ++rr) {
                    const float hvv = (&hv[rr].x)[kk];
                    accA[rr] = fmaf(hvv, wA[kk], accA[rr]);
                    accB[rr] = fmaf(hvv, wB[kk], accB[rr]);
                }
        }
        const float boA = b_out[pA];
        const float boB = hasB ? b_out[pB] : 0.0f;
#pragma unroll
        for (int rr = 0; rr < 8; ++rr) {
            const size_t orow = (size_t)(row0 + myrow + rr) * P_DIM;
            out[orow + pA] = accA[rr] + boA;
            if (hasB) out[orow + pB] = accB[rr] + boB;
        }
    }
}

// -------- fp32 fallback — used only if ws_size is too small.
__global__ __launch_bounds__(256, 1)
void gru_fallback(const float* __restrict__ x,
                  const float* __restrict__ W_ih,
                  const float* __restrict__ Whh,
                  const float* __restrict__ b_ih,
                  const float* __restrict__ b_hh,
                  const float* __restrict__ Wout,
                  const float* __restrict__ b_out,
                  float* __restrict__ out) {
    __shared__ float hbuf[2][TB][H_DIM];

    const int tid   = threadIdx.x;
    const int cid   = tid & 63;
    const int rid   = tid >> 6;
    const int row0  = blockIdx.x * TB;
    const int myrow = rid * 8;
    const int c0    = cid * 4;

    float wih[3][4], bc[2][4], bihn[4], bhhn[4];
#pragma unroll
    for (int cc = 0; cc < 4; ++cc) {
        const int j = c0 + cc;
        wih[0][cc] = W_ih[j];
        wih[1][cc] = W_ih[H_DIM + j];
        wih[2][cc] = W_ih[2 * H_DIM + j];
        bc[0][cc]  = b_ih[j] + b_hh[j];
        bc[1][cc]  = b_ih[H_DIM + j] + b_hh[H_DIM + j];
        bihn[cc]   = b_ih[2 * H_DIM + j];
        bhhn[cc]   = b_hh[2 * H_DIM + j];
    }
    for (int i = tid; i < TB * H_DIM; i += 256) (&hbuf[0][0][0])[i] = 0.0f;
    float h_own[8][4];
#pragma unroll
    for (int rr = 0; rr < 8; ++rr)
#pragma unroll
        for (int cc = 0; cc < 4; ++cc) h_own[rr][cc] = 0.0f;
    __syncthreads();

    int p = 0;
    for (int t = 0; t < S_LEN; ++t) {
        float xv[8];
#pragma unroll
        for (int rr = 0; rr < 8; ++rr)
            xv[rr] = x[(size_t)(row0 + myrow + rr) * S_LEN + t];

        float acc[3][8][4];
#pragma unroll
        for (int rr = 0; rr < 8; ++rr)
#pragma unroll
            for (int cc = 0; cc < 4; ++cc) {
                acc[0][rr][cc] = fmaf(xv[rr], wih[0][cc], bc[0][cc]);
                acc[1][rr][cc] = fmaf(xv[rr], wih[1][cc], bc[1][cc]);
                acc[2][rr][cc] = bhhn[cc];
            }
        const float* hb = &hbuf[p][0][0];
        for (int k = 0; k < H_DIM; k += 4) {
            float4 hv[8];
#pragma unroll
            for (int rr = 0; rr < 8; ++rr)
                hv[rr] = *(const float4*)(hb + (myrow + rr) * H_DIM + k);
#pragma unroll
            for (int g = 0; g < 3; ++g)
#pragma unroll
                for (int kk = 0; kk < 4; ++kk) {
                    float wrow[4];
#pragma unroll
                    for (int cc = 0; cc < 4; ++cc)
                        wrow[cc] = Whh[(size_t)(g * H_DIM + c0 + cc) * H_DIM + k + kk];
#pragma unroll
                    for (int rr = 0; rr < 8; ++rr) {
                        const float hvv = (&hv[rr].x)[kk];
#pragma unroll
                        for (int cc = 0; cc < 4; ++cc)
                            acc[g][rr][cc] = fmaf(hvv, wrow[cc], acc[g][rr][cc]);
                    }
                }
        }
#pragma unroll
        for (int rr = 0; rr < 8; ++rr) {
            float4 hnew;
#pragma unroll
            for (int cc = 0; cc < 4; ++cc) {
                const float r_  = sigmoid_fast(acc[0][rr][cc]);
                const float z_  = sigmoid_fast(acc[1][rr][cc]);
                const float i_n = fmaf(xv[rr], wih[2][cc], bihn[cc]);
                const float n_  = tanh_fast(fmaf(r_, acc[2][rr][cc], i_n));
                const float hv2 = (1.0f - z_) * n_ + z_ * h_own[rr][cc];
                h_own[rr][cc] = hv2;
                (&hnew.x)[cc] = hv2;
            }
            *(float4*)&hbuf[1 - p][myrow + rr][c0] = hnew;
        }
        __syncthreads();
        p ^= 1;
    }

    const int  pA   = cid;
    const int  pB   = 64 + cid;
    const bool hasB = (cid < 32);
    float accA[8], accB[8];
#pragma unroll
    for (int rr = 0; rr < 8; ++rr) { accA[rr] = 0.0f; accB[rr] = 0.0f; }
    for (int k = 0; k < H_DIM; k += 4) {
        float4 hv[8];
#pragma unroll
        for (int rr = 0; rr < 8; ++rr)
            hv[rr] = *(const float4*)&hbuf[p][myrow + rr][k];
        float wA[4], wB[4];
#pragma unroll
        for (int kk = 0; kk < 4; ++kk) {
            wA[kk] = Wout[(size_t)pA * H_DIM + k + kk];
            wB[kk] = hasB ? Wout[(size_t)pB * H_DIM + k + kk] : 0.0f;
        }
#pragma unroll
        for (int kk = 0; kk < 4; ++kk)
#pragma unroll
            for (int rr = 0; rr < 8; ++rr) {
                const float hvv = (&hv[rr].x)[kk];
                accA[rr] = fmaf(hvv, wA[kk], accA[rr]);
                accB[rr] = fmaf(hvv, wB[kk], accB[rr]);
            }
    }
    const float boA = b_out[pA];
    const float boB = hasB ? b_out[pB] : 0.0f;
#pragma unroll
    for (int rr = 0; rr < 8; ++rr) {
        const size_t orow = (size_t)(row0 + myrow + rr) * P_DIM;
        out[orow + pA] = accA[rr] + boA;
        if (hasB) out[orow + pB] = accB[rr] + boB;
    }
}

extern "C" void kernel_launch(void* const* d_in, const int* in_sizes, int n_in,
                              void* d_out, int out_size, void* d_ws, size_t ws_size,
                              hipStream_t stream) {
    const float* x     = (const float*)d_in[0];
    const float* W_ih  = (const float*)d_in[1];
    const float* W_hh  = (const float*)d_in[2];
    const float* b_ih  = (const float*)d_in[3];
    const float* b_hh  = (const float*)d_in[4];
    const float* W_out = (const float*)d_in[5];
    const float* b_out = (const float*)d_in[6];
    float* out = (float*)d_out;

    const size_t bpack_elems = 8 * 48 * 64 * 8;          // 196608 bf16 per matrix
    const size_t wot_elems   = (size_t)H_DIM * P_DIM;    // 24576 fp32
    const size_t ctr_off = bpack_elems * 2 * sizeof(unsigned short) * 2 +
                           wot_elems * sizeof(float);    // 1671168 B (16-aligned)
    const size_t need = ctr_off + sizeof(unsigned int);

    if (ws_size >= need) {
        unsigned short* Bh = (unsigned short*)d_ws;
        unsigned short* Bl = Bh + bpack_elems * 2;
        float* WoT = (float*)(Bl + bpack_elems * 2);
        unsigned int* ctr = (unsigned int*)((char*)d_ws + ctr_off);
        pack_weights<<<G3, H_DIM, 0, stream>>>(W_hh, W_out, Bh, Bl, WoT, ctr);
        gru_mfma<<<B_ROWS / TB, 512, 0, stream>>>(x, W_ih, b_ih, b_hh,
                                                  Bh, Bl, WoT, b_out, out, ctr);
    } else {
        gru_fallback<<<B_ROWS / TB, 256, 0, stream>>>(x, W_ih, W_hh, b_ih, b_hh,
                                                      W_out, b_out, out);
    }
}

// Round 9
// 8837.148 us; speedup vs baseline: 1.0005x; 1.0005x over previous
//
#include <hip/hip_runtime.h>
#include <math.h>

// Problem constants
#define B_ROWS 8192
#define S_LEN  512
#define H_DIM  256
#define G3     768          // 3*H
#define P_DIM  96
#define TB     32           // batch rows per block

typedef __attribute__((ext_vector_type(8))) short short8;   // 8 bf16 (4 VGPRs)
typedef __attribute__((ext_vector_type(4))) float floatx4;  // MFMA C/D frag

__device__ __forceinline__ float sigmoid_fast(float v) {
    return 1.0f / (1.0f + __expf(-v));
}
__device__ __forceinline__ float tanh_fast(float v) {
    return 1.0f - 2.0f / (__expf(2.0f * v) + 1.0f);
}
__device__ __forceinline__ unsigned short f32_bf16_rtn(float f) {
    unsigned int u = __float_as_uint(f);
    u += 0x7fffu + ((u >> 16) & 1u);   // round-to-nearest-even
    return (unsigned short)(u >> 16);
}
__device__ __forceinline__ float bf16_f32(unsigned short h) {
    return __uint_as_float(((unsigned int)h) << 16);
}

// -------- One-time weight pack: W_hh -> per-lane MFMA B-fragments (hi/lo bf16).
// B[k][n] = W_hh[n][k].  16x16x32 B-frag: lane holds B[n=lane&15][k=quad*8+j].
// Tile index = (k>>5)*48 + (j>>4); lane = (j&15) | (((k>>3)&3)<<4); short = k&7.
// Also WoT[k][p] = W_out[p][k]; also zeroes the phase-sync counter.
__global__ void pack_weights(const float* __restrict__ W_hh,
                             const float* __restrict__ W_out,
                             unsigned short* __restrict__ Bh,
                             unsigned short* __restrict__ Bl,
                             float* __restrict__ WoT,
                             unsigned int* __restrict__ ctr) {
    const int j = blockIdx.x;    // gate col 0..767
    const int k = threadIdx.x;   // h idx   0..255
    const float wv = W_hh[j * H_DIM + k];
    const unsigned short hi = f32_bf16_rtn(wv);
    const unsigned short lo = f32_bf16_rtn(wv - bf16_f32(hi));
    const int idx = (((k >> 5) * 48 + (j >> 4)) * 64 +
                     ((j & 15) | (((k >> 3) & 3) << 4))) * 8 + (k & 7);
    Bh[idx] = hi;
    Bl[idx] = lo;
    if (j < P_DIM) WoT[k * P_DIM + j] = W_out[j * H_DIM + k];
    if (j == 0 && k == 0) *ctr = 0u;   // d_ws is re-poisoned every launch
}

// LDS layout (~148 KiB):
//   [0,       65536)  A-fragments, double-buffered: buf*32768 + (hi/lo)*16384
//                     + chunk(kc*2+mt)*1024 + slot*16 + short*2, slot = g(row),
//                     g(v) = v ^ ((v>>2)&7)  (reads conflict-free per 8-lane
//                     group, writes hit 8 distinct bank groups)
//   [65536,   69888)  xtile[2][32][17] fp32 (stride 17 kills bcast conflicts)
//   [69888,  151808)  W cache: 80 tiles x 1 KiB
//                     slots 0..47  = kc=6 lo  (index g*16 + w*2 + ht)
//                     slots 48..79 = kc=5 hi, g<2 (index g*16 + w*2 + ht)
#define A_OFF   0
#define X_OFF   65536
#define W_OFF   69888
#define LDS_SZ  151808
#define XSTR    17

union U16 { uint4 u; short8 s; };

__device__ __forceinline__ void mfma3(floatx4& c0, floatx4& c1,
                                      const short8& ah0, const short8& ah1,
                                      const short8& al0, const short8& al1,
                                      const short8& bh, const short8& bl) {
    c0 = __builtin_amdgcn_mfma_f32_16x16x32_bf16(ah0, bh, c0, 0, 0, 0);
    c1 = __builtin_amdgcn_mfma_f32_16x16x32_bf16(ah1, bh, c1, 0, 0, 0);
    c0 = __builtin_amdgcn_mfma_f32_16x16x32_bf16(al0, bh, c0, 0, 0, 0);
    c1 = __builtin_amdgcn_mfma_f32_16x16x32_bf16(al1, bh, c1, 0, 0, 0);
    c0 = __builtin_amdgcn_mfma_f32_16x16x32_bf16(ah0, bl, c0, 0, 0, 0);
    c1 = __builtin_amdgcn_mfma_f32_16x16x32_bf16(ah1, bl, c1, 0, 0, 0);
}

// A-frag reads for chunk kc_ (4 x ds_read_b128, swizzled rows).
#define READ_A(kc_) {                                                \
    const int cb = ((kc_) * 2) << 10;                                \
    ah0 = *(const short8*)(Ah + cb + rl16);                          \
    ah1 = *(const short8*)(Ah + cb + 1024 + rl16);                   \
    al0 = *(const short8*)(Al + cb + rl16);                          \
    al1 = *(const short8*)(Al + cb + 1024 + rl16); }

// Issue the 6 loads (3 gh, hi+lo) of half-group ghb_ of chunk kc_ into G_.
#define LOAD_G(G_, kc_, ghb_) {                                      \
    const size_t kb = (size_t)(kc_) * 49152;                         \
    _Pragma("unroll") for (int i_ = 0; i_ < 3; ++i_) {               \
        G_[2 * i_].u     = *(const uint4*)(BhB + kb + boff[(ghb_) + i_]); \
        G_[2 * i_ + 1].u = *(const uint4*)(BlB + kb + boff[(ghb_) + i_]); \
    } }

// 18 MFMAs consuming half-group G_ (gh = ghb_..ghb_+2) with current A-frags.
#define MFMA_G(G_, ghb_)                                             \
    _Pragma("unroll") for (int i_ = 0; i_ < 3; ++i_) {               \
        mfma3(acc[((ghb_) + i_) >> 1][0][((ghb_) + i_) & 1],         \
              acc[((ghb_) + i_) >> 1][1][((ghb_) + i_) & 1],         \
              ah0, ah1, al0, al1, G_[2 * i_].s, G_[2 * i_ + 1].s);   \
    }

// kc=5 streamed remainders: P gets gh0-3 lo; Q gets gh4,5 hi+lo.
#define LOAD_K5P(P_) { const size_t kb = (size_t)5 * 49152;          \
    _Pragma("unroll") for (int i_ = 0; i_ < 4; ++i_)                 \
        P_[i_].u = *(const uint4*)(BlB + kb + boff[i_]); }
#define LOAD_K5Q(Q_) { const size_t kb = (size_t)5 * 49152;          \
    Q_[0].u = *(const uint4*)(BhB + kb + boff[4]);                   \
    Q_[1].u = *(const uint4*)(BlB + kb + boff[4]);                   \
    Q_[2].u = *(const uint4*)(BhB + kb + boff[5]);                   \
    Q_[3].u = *(const uint4*)(BlB + kb + boff[5]); }

// Main persistent GRU kernel: split-bf16 MFMA + partial weight residency +
// half-kc software pipeline.
// __launch_bounds__(512, 1): R3-R8 used (512,2), which capped the allocator
// at 128 arch VGPRs — every pipelining attempt (R5/R6/R8) spilled to scratch
// (multi-GB FETCH of spill reloads).  LDS (148 KiB -> 1 block/CU) already
// pins runtime occupancy at 2 waves/SIMD, so relaxing the bound only gives
// the allocator headroom (~256/wave); it does not reduce real occupancy.
// grid = 256 (1 block/CU), block = 512 (8 waves).
__global__ __launch_bounds__(512, 1)
void gru_mfma(const float* __restrict__ x,
              const float* __restrict__ W_ih,
              const float* __restrict__ b_ih,
              const float* __restrict__ b_hh,
              const unsigned short* __restrict__ Bh,
              const unsigned short* __restrict__ Bl,
              const float* __restrict__ WoT,   // [256][96]
              const float* __restrict__ b_out,
              float* __restrict__ out,
              unsigned int* __restrict__ ctr) {
    __shared__ __align__(16) char smem[LDS_SZ];

    const int tid  = threadIdx.x;
    const int w    = tid >> 6;     // wave 0..7
    const int lane = tid & 63;
    const int q    = lane >> 4;    // quad
    const int c    = lane & 15;
    const int row0 = blockIdx.x * TB;

    const char* BhB = (const char*)Bh;
    const char* BlB = (const char*)Bl;

    // Per-thread gate params; col = 256*g + 32*w + 16*ht + c
    float wih[3][2], bcc[2][2], bihn[2], bhhn[2];
#pragma unroll
    for (int g = 0; g < 3; ++g)
#pragma unroll
        for (int ht = 0; ht < 2; ++ht) {
            const int col = g * H_DIM + w * 32 + ht * 16 + c;
            wih[g][ht] = W_ih[col];
            if (g < 2) {
                bcc[g][ht] = b_ih[col] + b_hh[col];
            } else {
                bihn[ht] = b_ih[col];
                bhhn[ht] = b_hh[col];
            }
        }

    // 32-bit per-lane tile offsets (gh = g*2 + ht); chunk kc adds kc*49152.
    unsigned int boff[6];
#pragma unroll
    for (int gh = 0; gh < 6; ++gh)
        boff[gh] = (unsigned)((((gh >> 1) * 16 + w * 2 + (gh & 1)) << 10) + (lane << 4));

    // Register-resident weight tiles: kc=7 hi+lo, kc=6 hi.  (72 VGPRs)
    short8 r7h[6], r7l[6], r6h[6];
#pragma unroll
    for (int gh = 0; gh < 6; ++gh) {
        U16 a, b, d;
        a.u = *(const uint4*)(BhB + (size_t)7 * 49152 + boff[gh]);
        b.u = *(const uint4*)(BlB + (size_t)7 * 49152 + boff[gh]);
        d.u = *(const uint4*)(BhB + (size_t)6 * 49152 + boff[gh]);
        r7h[gh] = a.s; r7l[gh] = b.s; r6h[gh] = d.s;
    }

    // LDS weight cache staging: 80 tiles (kc=6 lo: Bl tiles 288..335;
    // kc=5 hi g<2: Bh tiles 240..271).
    for (int i = tid; i < 80 * 64; i += 512) {
        const int slot = i >> 6, l16 = i & 63;
        const unsigned short* src = (slot < 48)
            ? (Bl + (size_t)(288 + slot) * 512 + l16 * 8)
            : (Bh + (size_t)(240 + slot - 48) * 512 + l16 * 8);
        *(uint4*)(smem + W_OFF + slot * 1024 + l16 * 16) = *(const uint4*)src;
    }

    // Zero both A-frag buffers (h0 = 0) and stage x for t=0..15.
    for (int i = tid; i < 16384; i += 512) ((int*)(smem + A_OFF))[i] = 0;
    float* xt = (float*)(smem + X_OFF);
    {
        const int r = tid >> 4, t2 = tid & 15;
        xt[r * XSTR + t2] = x[(size_t)(row0 + r) * S_LEN + t2];
    }
    __syncthreads();

    // h_old in C-frag layout: element (mt,ht,reg) = h[4q+reg+16mt][32w+16ht+c]
    float h_own[2][2][4];
#pragma unroll
    for (int mt = 0; mt < 2; ++mt)
#pragma unroll
        for (int ht = 0; ht < 2; ++ht)
#pragma unroll
            for (int r = 0; r < 4; ++r) h_own[mt][ht][r] = 0.0f;

    // Swizzle g(v) = v ^ ((v>>2)&7): reads conflict-free per aligned 8-lane
    // group; writer dest rows hit 8 distinct bank groups per store.
    const int rl16 = (lane ^ ((lane >> 2) & 7)) << 4;
    const int gxor = q + 4 * (c >> 3);       // == (d>>2)&7, thread-constant

    for (int t = 0; t < S_LEN; ++t) {
        const int cur = t & 1, nxt = cur ^ 1;
        const char* Ah = smem + A_OFF + cur * 32768;
        const char* Al = Ah + 16384;

        // x for my 8 rows (LDS broadcast, conflict-free via XSTR=17)
        float xr[2][4];
#pragma unroll
        for (int mt = 0; mt < 2; ++mt)
#pragma unroll
            for (int r = 0; r < 4; ++r)
                xr[mt][r] = xt[(((t >> 4) & 1) * 32 + q * 4 + r + 16 * mt) * XSTR + (t & 15)];

        // C frags [gate][mt][ht]; fold x-side pre-activation + bias into init.
        floatx4 acc[3][2][2];
#pragma unroll
        for (int mt = 0; mt < 2; ++mt)
#pragma unroll
            for (int ht = 0; ht < 2; ++ht)
#pragma unroll
                for (int r = 0; r < 4; ++r) {
                    acc[0][mt][ht][r] = fmaf(xr[mt][r], wih[0][ht], bcc[0][ht]);
                    acc[1][mt][ht][r] = fmaf(xr[mt][r], wih[1][ht], bcc[1][ht]);
                    acc[2][mt][ht][r] = bhhn[ht];
                }

        U16 P[6], Q[6];
        short8 ah0, ah1, al0, al1;

        // ---- Prologue: issue kc0's two half-groups, hide their latency
        // under the register/LDS-resident chunks kc7 and kc6. ----
        LOAD_G(P, 0, 0)
        READ_A(7)
#pragma unroll
        for (int gh = 0; gh < 6; ++gh)
            mfma3(acc[gh >> 1][0][gh & 1], acc[gh >> 1][1][gh & 1],
                  ah0, ah1, al0, al1, r7h[gh], r7l[gh]);
        LOAD_G(Q, 0, 3)
        READ_A(6)
#pragma unroll
        for (int gh = 0; gh < 6; ++gh) {
            const int slot = (gh >> 1) * 16 + w * 2 + (gh & 1);
            short8 bl = *(const short8*)(smem + W_OFF + slot * 1024 + lane * 16);
            mfma3(acc[gh >> 1][0][gh & 1], acc[gh >> 1][1][gh & 1],
                  ah0, ah1, al0, al1, r6h[gh], bl);
        }

        // ---- kc = 0..3: half-kc ping-pong pipeline.  Consume P, refill P
        // for kc+1 (in flight across MFMA_G(Q) + next iteration). ----
#pragma unroll 1
        for (int kc = 0; kc < 4; ++kc) {
            READ_A(kc)
            MFMA_G(P, 0)
            LOAD_G(P, kc + 1, 0)
            MFMA_G(Q, 3)
            LOAD_G(Q, kc + 1, 3)
        }

        // ---- kc = 4: consume, refill with kc5's streamed remainders ----
        READ_A(4)
        MFMA_G(P, 0)
        LOAD_K5P(P)
        MFMA_G(Q, 3)
        LOAD_K5Q(Q)

        // ---- kc = 5: hi g<2 from LDS cache; rest from P/Q ----
        READ_A(5)
#pragma unroll
        for (int gh = 0; gh < 4; ++gh) {
            const int slot = 48 + (gh >> 1) * 16 + w * 2 + (gh & 1);
            short8 bh = *(const short8*)(smem + W_OFF + slot * 1024 + lane * 16);
            mfma3(acc[gh >> 1][0][gh & 1], acc[gh >> 1][1][gh & 1],
                  ah0, ah1, al0, al1, bh, P[gh].s);
        }
        mfma3(acc[2][0][0], acc[2][1][0], ah0, ah1, al0, al1, Q[0].s, Q[1].s);
        mfma3(acc[2][0][1], acc[2][1][1], ah0, ah1, al0, al1, Q[2].s, Q[3].s);

        // Gates + h update (in-register); scatter next A-frags (g-swizzled).
        char* Anx = smem + A_OFF + nxt * 32768;
#pragma unroll
        for (int mt = 0; mt < 2; ++mt) {
            char* chh = Anx + (w * 2 + mt) * 1024;          // hi chunk (kc=w)
            char* cll = chh + 16384;                        // lo chunk
#pragma unroll
            for (int ht = 0; ht < 2; ++ht)
#pragma unroll
                for (int r = 0; r < 4; ++r) {
                    const float rr  = sigmoid_fast(acc[0][mt][ht][r]);
                    const float zz  = sigmoid_fast(acc[1][mt][ht][r]);
                    const float inn = fmaf(xr[mt][r], wih[2][ht], bihn[ht]);
                    const float nn  = tanh_fast(fmaf(rr, acc[2][mt][ht][r], inn));
                    const float hv  = (1.0f - zz) * nn + zz * h_own[mt][ht][r];
                    h_own[mt][ht][r] = hv;
                    const unsigned short hi = f32_bf16_rtn(hv);
                    // lo truncated (error 2^-17-relative, invisible vs 2^-11)
                    const unsigned short lo =
                        (unsigned short)(__float_as_uint(hv - bf16_f32(hi)) >> 16);
                    const int d   = (q * 4 + r) | ((2 * ht + (c >> 3)) << 4);
                    const int off = ((d ^ gxor) << 4) + ((c & 7) << 1);
                    *(unsigned short*)(chh + off) = hi;
                    *(unsigned short*)(cll + off) = lo;
                }
        }

        // Re-stage x for the next 16 steps (into the idle x buffer).
        const bool tick = ((t & 15) == 15) && (t != S_LEN - 1);
        if (tick) {
            const int r = tid >> 4, t2 = tid & 15;
            xt[((((t + 1) >> 4) & 1) * 32 + r) * XSTR + t2] =
                x[(size_t)(row0 + r) * S_LEN + (t + 1) + t2];
        }
        __syncthreads();   // single barrier: next A-frags + x tile visible

        // Phase-alignment heartbeat every 16 steps: keeps all 256 blocks'
        // weight streams in phase so per-XCD L2 stays hot.  Pure timing
        // hint — bounded spin, no data dependency.
        if (tick) {
            if (tid == 0) {
                const unsigned int tgt = 256u * (unsigned)((t >> 4) + 1);
                atomicAdd(ctr, 1u);
                for (int spin = 0; spin < (1 << 17); ++spin) {
                    if (__hip_atomic_load(ctr, __ATOMIC_RELAXED,
                                          __HIP_MEMORY_SCOPE_AGENT) >= tgt) break;
                    __builtin_amdgcn_s_sleep(4);
                }
            }
            __syncthreads();
        }
    }

    // -------- Epilogue: dump final h (fp32, from registers) and project.
    float* hfin = (float*)(smem);   // reuse A region: [32][256]
#pragma unroll
    for (int mt = 0; mt < 2; ++mt)
#pragma unroll
        for (int ht = 0; ht < 2; ++ht)
#pragma unroll
            for (int r = 0; r < 4; ++r) {
                const int m = q * 4 + r + 16 * mt;
                const int k = w * 32 + ht * 16 + c;
                hfin[m * H_DIM + k] = h_own[mt][ht][r];
            }
    __syncthreads();

    if (tid < 256) {
        const int cid   = tid & 63;
        const int rid   = tid >> 6;
        const int myrow = rid * 8;
        const int pA    = cid;
        const int pB    = 64 + cid;
        const bool hasB = (cid < 32);
        float accA[8], accB[8];
#pragma unroll
        for (int rr = 0; rr < 8; ++rr) { accA[rr] = 0.0f; accB[rr] = 0.0f; }

        for (int k = 0; k < H_DIM; k += 4) {
            float4 hv[8];
#pragma unroll
            for (int rr = 0; rr < 8; ++rr)
                hv[rr] = *(const float4*)&hfin[(myrow + rr) * H_DIM + k];
            float wA[4], wB[4];
#pragma unroll
            for (int kk = 0; kk < 4; ++kk) {
                wA[kk] = WoT[(size_t)(k + kk) * P_DIM + pA];
                wB[kk] = hasB ? WoT[(size_t)(k + kk) * P_DIM + pB] : 0.0f;
            }
#pragma unroll
            for (int kk = 0; kk < 4; ++kk)
#pragma unroll
                for (int rr = 0; rr < 8; ++rr) {
                    const float hvv = (&hv[rr].x)[kk];
                    accA[rr] = fmaf(hvv, wA[kk], accA[rr]);
                    accB[rr] = fmaf(hvv, wB[kk], accB[rr]);
                }
        }
        const float boA = b_out[pA];
        const float boB = hasB ? b_out[pB] : 0.0f;
#pragma unroll
        for (int rr = 0; rr < 8; ++rr) {
            const size_t orow = (size_t)(row0 + myrow + rr) * P_DIM;
            out[orow + pA] = accA[rr] + boA;
            if (hasB) out[orow + pB] = accB[rr] + boB;
        }
    }
}

// -------- fp32 fallback — used only if ws_size is too small.
__global__ __launch_bounds__(256, 1)
void gru_fallback(const float* __restrict__ x,
                  const float* __restrict__ W_ih,
                  const float* __restrict__ Whh,
                  const float* __restrict__ b_ih,
                  const float* __restrict__ b_hh,
                  const float* __restrict__ Wout,
                  const float* __restrict__ b_out,
                  float* __restrict__ out) {
    __shared__ float hbuf[2][TB][H_DIM];

    const int tid   = threadIdx.x;
    const int cid   = tid & 63;
    const int rid   = tid >> 6;
    const int row0  = blockIdx.x * TB;
    const int myrow = rid * 8;
    const int c0    = cid * 4;

    float wih[3][4], bc[2][4], bihn[4], bhhn[4];
#pragma unroll
    for (int cc = 0; cc < 4; ++cc) {
        const int j = c0 + cc;
        wih[0][cc] = W_ih[j];
        wih[1][cc] = W_ih[H_DIM + j];
        wih[2][cc] = W_ih[2 * H_DIM + j];
        bc[0][cc]  = b_ih[j] + b_hh[j];
        bc[1][cc]  = b_ih[H_DIM + j] + b_hh[H_DIM + j];
        bihn[cc]   = b_ih[2 * H_DIM + j];
        bhhn[cc]   = b_hh[2 * H_DIM + j];
    }
    for (int i = tid; i < TB * H_DIM; i += 256) (&hbuf[0][0][0])[i] = 0.0f;
    float h_own[8][4];
#pragma unroll
    for (int rr = 0; rr < 8; ++rr)
#pragma unroll
        for (int cc = 0; cc < 4; ++cc) h_own[rr][cc] = 0.0f;
    __syncthreads();

    int p = 0;
    for (int t = 0; t < S_LEN; ++t) {
        float xv[8];
#pragma unroll
        for (int rr = 0; rr < 8; ++rr)
            xv[rr] = x[(size_t)(row0 + myrow + rr) * S_LEN + t];

        float acc[3][8][4];
#pragma unroll
        for (int rr = 0; rr < 8; ++rr)
#pragma unroll
            for (int cc = 0; cc < 4; ++cc) {
                acc[0][rr][cc] = fmaf(xv[rr], wih[0][cc], bc[0][cc]);
                acc[1][rr][cc] = fmaf(xv[rr], wih[1][cc], bc[1][cc]);
                acc[2][rr][cc] = bhhn[cc];
            }
        const float* hb = &hbuf[p][0][0];
        for (int k = 0; k < H_DIM; k += 4) {
            float4 hv[8];
#pragma unroll
            for (int rr = 0; rr < 8; ++rr)
                hv[rr] = *(const float4*)(hb + (myrow + rr) * H_DIM + k);
#pragma unroll
            for (int g = 0; g < 3; ++g)
#pragma unroll
                for (int kk = 0; kk < 4; ++kk) {
                    float wrow[4];
#pragma unroll
                    for (int cc = 0; cc < 4; ++cc)
                        wrow[cc] = Whh[(size_t)(g * H_DIM + c0 + cc) * H_DIM + k + kk];
#pragma unroll
                    for (int rr = 0; rr < 8; ++rr) {
                        const float hvv = (&hv[rr].x)[kk];
#pragma unroll
                        for (int cc = 0; cc < 4; ++cc)
                            acc[g][rr][cc] = fmaf(hvv, wrow[cc], acc[g][rr][cc]);
                    }
                }
        }
#pragma unroll
        for (int rr = 0; rr < 8; ++rr) {
            float4 hnew;
#pragma unroll
            for (int cc = 0; cc < 4; ++cc) {
                const float r_  = sigmoid_fast(acc[0][rr][cc]);
                const float z_  = sigmoid_fast(acc[1][rr][cc]);
                const float i_n = fmaf(xv[rr], wih[2][cc], bihn[cc]);
                const float n_  = tanh_fast(fmaf(r_, acc[2][rr][cc], i_n));
                const float hv2 = (1.0f - z_) * n_ + z_ * h_own[rr][cc];
                h_own[rr][cc] = hv2;
                (&hnew.x)[cc] = hv2;
            }
            *(float4*)&hbuf[1 - p][myrow + rr][c0] = hnew;
        }
        __syncthreads();
        p ^= 1;
    }

    const int  pA   = cid;
    const int  pB   = 64 + cid;
    const bool hasB = (cid < 32);
    float accA[8], accB[8];
#pragma unroll
    for (int rr = 0; rr < 8; ++rr) { accA[rr] = 0.0f; accB[rr] = 0.0f; }
    for (int k = 0; k < H_DIM; k += 4) {
        float4 hv[8];
#pragma unroll
        for (int rr = 0; rr < 8; ++rr)
            hv[rr] = *(const float4*)&hbuf[p][myrow + rr][k];
        float wA[4], wB[4];
#pragma unroll
        for (int kk = 0; kk < 4; ++kk) {
            wA[kk] = Wout[(size_t)pA * H_DIM + k + kk];
            wB[kk] = hasB ? Wout[(size_t)pB * H_DIM + k + kk] : 0.0f;
        }
#pragma unroll
        for (int kk = 0; kk < 4; ++kk)
#pragma unroll
            for (int rr = 0; rr < 8; ++rr) {
                const float hvv = (&hv[rr].x)[kk];
                accA[rr] = fmaf(hvv, wA[kk], accA[rr]);
                accB[rr] = fmaf(hvv, wB[kk], accB[rr]);
            }
    }
    const float boA = b_out[pA];
    const float boB = hasB ? b_out[pB] : 0.0f;
#pragma unroll
    for (int rr = 0; rr < 8; ++rr) {
        const size_t orow = (size_t)(row0 + myrow + rr) * P_DIM;
        out[orow + pA] = accA[rr] + boA;
        if (hasB) out[orow + pB] = accB[rr] + boB;
    }
}

extern "C" void kernel_launch(void* const* d_in, const int* in_sizes, int n_in,
                              void* d_out, int out_size, void* d_ws, size_t ws_size,
                              hipStream_t stream) {
    const float* x     = (const float*)d_in[0];
    const float* W_ih  = (const float*)d_in[1];
    const float* W_hh  = (const float*)d_in[2];
    const float* b_ih  = (const float*)d_in[3];
    const float* b_hh  = (const float*)d_in[4];
    const float* W_out = (const float*)d_in[5];
    const float* b_out = (const float*)d_in[6];
    float* out = (float*)d_out;

    const size_t bpack_elems = 8 * 48 * 64 * 8;          // 196608 bf16 per matrix
    const size_t wot_elems   = (size_t)H_DIM * P_DIM;    // 24576 fp32
    const size_t ctr_off = bpack_elems * 2 * sizeof(unsigned short) * 2 +
                           wot_elems * sizeof(float);    // 1671168 B (16-aligned)
    const size_t need = ctr_off + sizeof(unsigned int);

    if (ws_size >= need) {
        unsigned short* Bh = (unsigned short*)d_ws;
        unsigned short* Bl = Bh + bpack_elems * 2;
        float* WoT = (float*)(Bl + bpack_elems * 2);
        unsigned int* ctr = (unsigned int*)((char*)d_ws + ctr_off);
        pack_weights<<<G3, H_DIM, 0, stream>>>(W_hh, W_out, Bh, Bl, WoT, ctr);
        gru_mfma<<<B_ROWS / TB, 512, 0, stream>>>(x, W_ih, b_ih, b_hh,
                                                  Bh, Bl, WoT, b_out, out, ctr);
    } else {
        gru_fallback<<<B_ROWS / TB, 256, 0, stream>>>(x, W_ih, W_hh, b_ih, b_hh,
                                                      W_out, b_out, out);
    }
}